// Round 2
// baseline (2627.460 us; speedup 1.0000x reference)
//
#include <hip/hip_runtime.h>
#include <stdint.h>

#define B_DIM 16384
#define V_DIM 1024
#define H_DIM 256
#define K_STEPS 8

// ---------------- Threefry-2x32-20, bit-exact JAX replica ----------------
__host__ __device__ inline uint32_t rotl32(uint32_t v, int r) {
    return (v << r) | (v >> (32 - r));
}

__host__ __device__ inline void threefry2x32(uint32_t k0, uint32_t k1,
                                             uint32_t x0, uint32_t x1,
                                             uint32_t* o0, uint32_t* o1) {
    uint32_t k2 = k0 ^ k1 ^ 0x1BD11BDAu;
    x0 += k0; x1 += k1;
#define TF_RND(r) { x0 += x1; x1 = rotl32(x1, (r)); x1 ^= x0; }
    TF_RND(13) TF_RND(15) TF_RND(26) TF_RND(6)
    x0 += k1; x1 += k2 + 1u;
    TF_RND(17) TF_RND(29) TF_RND(16) TF_RND(24)
    x0 += k2; x1 += k0 + 2u;
    TF_RND(13) TF_RND(15) TF_RND(26) TF_RND(6)
    x0 += k0; x1 += k1 + 3u;
    TF_RND(17) TF_RND(29) TF_RND(16) TF_RND(24)
    x0 += k1; x1 += k2 + 4u;
    TF_RND(13) TF_RND(15) TF_RND(26) TF_RND(6)
    x0 += k2; x1 += k0 + 5u;
#undef TF_RND
    *o0 = x0; *o1 = x1;
}

// Partitionable-threefry uniform: element e of a jax.random.uniform of size < 2^32.
// counter = 64-bit iota -> words (0, e); bits = o0 ^ o1; map to [0,1).
__device__ inline float tf_uniform(uint32_t key0, uint32_t key1, uint32_t e) {
    uint32_t o0, o1;
    threefry2x32(key0, key1, 0u, e, &o0, &o1);
    uint32_t bits = o0 ^ o1;
    return __uint_as_float((bits >> 9) | 0x3f800000u) - 1.0f;
}

// ---------------- GEMM + activation (+ optional sampling) ----------------
// C[row,col] = sum_k A[row,k]*Bm[k,col] + bias[col]; out = sample or sigmoid.
// Tile: 64 rows x 128 cols, BK=32; 256 threads, each 8x4 outputs.
template <int MODE>  // 0 = sigmoid+sample to {0,1}; 1 = store sigmoid
__global__ __launch_bounds__(256, 2) void gemm_act(
    const float* __restrict__ A, const float* __restrict__ Bm,
    const float* __restrict__ bias, float* __restrict__ out,
    int K, int N, uint32_t key0, uint32_t key1) {
    __shared__ float As[32][64];
    __shared__ float Bs[32][128];
    const int tid = threadIdx.x;
    const int row0 = blockIdx.x * 64;
    const int col0 = blockIdx.y * 128;

    float acc[8][4];
#pragma unroll
    for (int i = 0; i < 8; ++i)
#pragma unroll
        for (int j = 0; j < 4; ++j) acc[i][j] = 0.0f;

    const int am = tid >> 2;         // 0..63 row within tile
    const int ak = (tid & 3) * 8;    // k offset 0,8,16,24
    const int bk = tid >> 3;         // 0..31 k within chunk
    const int bc = (tid & 7) * 16;   // col offset
    const int tr = tid >> 5;         // 0..7
    const int tc = tid & 31;         // 0..31

    for (int k0 = 0; k0 < K; k0 += 32) {
        const float4* asrc = reinterpret_cast<const float4*>(
            &A[(size_t)(row0 + am) * K + k0 + ak]);
        float4 a0 = asrc[0], a1 = asrc[1];
        As[ak + 0][am] = a0.x; As[ak + 1][am] = a0.y;
        As[ak + 2][am] = a0.z; As[ak + 3][am] = a0.w;
        As[ak + 4][am] = a1.x; As[ak + 5][am] = a1.y;
        As[ak + 6][am] = a1.z; As[ak + 7][am] = a1.w;
        const float4* bsrc = reinterpret_cast<const float4*>(
            &Bm[(size_t)(k0 + bk) * N + col0 + bc]);
        float4* bdst = reinterpret_cast<float4*>(&Bs[bk][bc]);
        bdst[0] = bsrc[0]; bdst[1] = bsrc[1]; bdst[2] = bsrc[2]; bdst[3] = bsrc[3];
        __syncthreads();
#pragma unroll
        for (int kk = 0; kk < 32; ++kk) {
            float4 av0 = *reinterpret_cast<const float4*>(&As[kk][tr * 8]);
            float4 av1 = *reinterpret_cast<const float4*>(&As[kk][tr * 8 + 4]);
            float4 bv = *reinterpret_cast<const float4*>(&Bs[kk][tc * 4]);
            float a[8] = {av0.x, av0.y, av0.z, av0.w, av1.x, av1.y, av1.z, av1.w};
            float b[4] = {bv.x, bv.y, bv.z, bv.w};
#pragma unroll
            for (int i = 0; i < 8; ++i)
#pragma unroll
                for (int j = 0; j < 4; ++j) acc[i][j] = fmaf(a[i], b[j], acc[i][j]);
        }
        __syncthreads();
    }

#pragma unroll
    for (int i = 0; i < 8; ++i) {
        int row = row0 + tr * 8 + i;
#pragma unroll
        for (int j = 0; j < 4; ++j) {
            int col = col0 + tc * 4 + j;
            float pre = acc[i][j] + bias[col];
            float sg = 1.0f / (1.0f + expf(-pre));
            if (MODE == 0) {
                uint32_t e = (uint32_t)row * (uint32_t)N + (uint32_t)col;
                float u = tf_uniform(key0, key1, e);
                out[(size_t)row * N + col] = (u < sg) ? 1.0f : 0.0f;
            } else {
                out[(size_t)row * N + col] = sg;
            }
        }
    }
}

// ---------------- W transpose (V x H from H x V) ----------------
__global__ void transpose_w(const float* __restrict__ W, float* __restrict__ WT) {
    int idx = blockIdx.x * 256 + threadIdx.x;  // over H*V
    int h = idx >> 10;
    int j = idx & 1023;
    WT[j * H_DIM + h] = W[idx];
}

// ---------------- log-norm: inv[b] = exp(-(vk.vb + sum softplus(pre)))/B ----------------
// softplus(pre) = -log1p(-phk) exactly, since phk = sigmoid(pre).
__global__ __launch_bounds__(256) void lognorm_kernel(
    const float* __restrict__ phk, const float* __restrict__ vk,
    const float* __restrict__ vb, float* __restrict__ inv) {
    int b = blockIdx.x;
    int tid = threadIdx.x;
    float p = phk[(size_t)b * H_DIM + tid];
    float s = -log1pf(-p);
    for (int j = tid; j < V_DIM; j += 256)
        s += vk[(size_t)b * V_DIM + j] * vb[j];
    for (int off = 32; off > 0; off >>= 1) s += __shfl_down(s, off, 64);
    __shared__ float wsum[4];
    int lane = tid & 63, wid = tid >> 6;
    if (lane == 0) wsum[wid] = s;
    __syncthreads();
    if (tid == 0) {
        float t = wsum[0] + wsum[1] + wsum[2] + wsum[3];
        inv[b] = expf(-t) * (1.0f / 16384.0f);
    }
}

// ---------------- g_W: [H,V] = sum_b inv*phk outer vk - inv*ph0 outer batch ----------------
__global__ __launch_bounds__(256, 2) void gw_kernel(
    const float* __restrict__ phk, const float* __restrict__ ph0,
    const float* __restrict__ vk, const float* __restrict__ v0in,
    const float* __restrict__ inv, float* __restrict__ gw) {
    __shared__ float A1s[32][64];
    __shared__ float A2s[32][64];
    __shared__ float Bvs[32][128];
    __shared__ float Bbs[32][128];
    const int tid = threadIdx.x;
    const int h0 = blockIdx.x * 64;
    const int v0c = blockIdx.y * 128;
    const int bbase = blockIdx.z * (B_DIM / 16);  // 1024 rows per z-slice

    float acc[8][4];
#pragma unroll
    for (int i = 0; i < 8; ++i)
#pragma unroll
        for (int j = 0; j < 4; ++j) acc[i][j] = 0.0f;

    const int sk = tid >> 3;          // 0..31: b within chunk
    const int amb = (tid & 7) * 8;    // h offset
    const int bcb = (tid & 7) * 16;   // v offset
    const int tr = tid >> 5;
    const int tc = tid & 31;

    for (int b0 = 0; b0 < B_DIM / 16; b0 += 32) {
        int b = bbase + b0 + sk;
        float iv = inv[b];
        const float4* p1 = reinterpret_cast<const float4*>(&phk[(size_t)b * H_DIM + h0 + amb]);
        float4 x0 = p1[0], x1 = p1[1];
        A1s[sk][amb + 0] = iv * x0.x; A1s[sk][amb + 1] = iv * x0.y;
        A1s[sk][amb + 2] = iv * x0.z; A1s[sk][amb + 3] = iv * x0.w;
        A1s[sk][amb + 4] = iv * x1.x; A1s[sk][amb + 5] = iv * x1.y;
        A1s[sk][amb + 6] = iv * x1.z; A1s[sk][amb + 7] = iv * x1.w;
        const float4* p2 = reinterpret_cast<const float4*>(&ph0[(size_t)b * H_DIM + h0 + amb]);
        float4 y0 = p2[0], y1 = p2[1];
        A2s[sk][amb + 0] = iv * y0.x; A2s[sk][amb + 1] = iv * y0.y;
        A2s[sk][amb + 2] = iv * y0.z; A2s[sk][amb + 3] = iv * y0.w;
        A2s[sk][amb + 4] = iv * y1.x; A2s[sk][amb + 5] = iv * y1.y;
        A2s[sk][amb + 6] = iv * y1.z; A2s[sk][amb + 7] = iv * y1.w;
        const float4* pv = reinterpret_cast<const float4*>(&vk[(size_t)b * V_DIM + v0c + bcb]);
        float4* dv = reinterpret_cast<float4*>(&Bvs[sk][bcb]);
        dv[0] = pv[0]; dv[1] = pv[1]; dv[2] = pv[2]; dv[3] = pv[3];
        const float4* pb = reinterpret_cast<const float4*>(&v0in[(size_t)b * V_DIM + v0c + bcb]);
        float4* db = reinterpret_cast<float4*>(&Bbs[sk][bcb]);
        db[0] = pb[0]; db[1] = pb[1]; db[2] = pb[2]; db[3] = pb[3];
        __syncthreads();
#pragma unroll
        for (int kk = 0; kk < 32; ++kk) {
            float4 a10 = *reinterpret_cast<const float4*>(&A1s[kk][tr * 8]);
            float4 a11 = *reinterpret_cast<const float4*>(&A1s[kk][tr * 8 + 4]);
            float4 a20 = *reinterpret_cast<const float4*>(&A2s[kk][tr * 8]);
            float4 a21 = *reinterpret_cast<const float4*>(&A2s[kk][tr * 8 + 4]);
            float4 bv = *reinterpret_cast<const float4*>(&Bvs[kk][tc * 4]);
            float4 bb = *reinterpret_cast<const float4*>(&Bbs[kk][tc * 4]);
            float a1[8] = {a10.x, a10.y, a10.z, a10.w, a11.x, a11.y, a11.z, a11.w};
            float a2[8] = {a20.x, a20.y, a20.z, a20.w, a21.x, a21.y, a21.z, a21.w};
            float bvv[4] = {bv.x, bv.y, bv.z, bv.w};
            float bbv[4] = {bb.x, bb.y, bb.z, bb.w};
#pragma unroll
            for (int i = 0; i < 8; ++i)
#pragma unroll
                for (int j = 0; j < 4; ++j) {
                    acc[i][j] = fmaf(a1[i], bvv[j], acc[i][j]);
                    acc[i][j] = fmaf(-a2[i], bbv[j], acc[i][j]);
                }
        }
        __syncthreads();
    }
#pragma unroll
    for (int i = 0; i < 8; ++i)
#pragma unroll
        for (int j = 0; j < 4; ++j)
            atomicAdd(&gw[(size_t)(h0 + tr * 8 + i) * V_DIM + v0c + tc * 4 + j], acc[i][j]);
}

// ---------------- g_vb ----------------
__global__ void gvb_kernel(const float* __restrict__ vk, const float* __restrict__ v0in,
                           const float* __restrict__ inv, float* __restrict__ gvb) {
    int col = blockIdx.x * 256 + threadIdx.x;
    int b0 = blockIdx.y * 512;
    float acc = 0.0f;
    for (int r = 0; r < 512; ++r) {
        int b = b0 + r;
        acc += inv[b] * (vk[(size_t)b * V_DIM + col] - v0in[(size_t)b * V_DIM + col]);
    }
    atomicAdd(&gvb[col], acc);
}

// ---------------- g_hb ----------------
__global__ void ghb_kernel(const float* __restrict__ phk, const float* __restrict__ ph0,
                           const float* __restrict__ inv, float* __restrict__ ghb) {
    int col = threadIdx.x;  // 256
    int b0 = blockIdx.x * 256;
    float acc = 0.0f;
    for (int r = 0; r < 256; ++r) {
        int b = b0 + r;
        acc += inv[b] * (phk[b * H_DIM + col] - ph0[b * H_DIM + col]);
    }
    atomicAdd(&ghb[col], acc);
}

extern "C" void kernel_launch(void* const* d_in, const int* in_sizes, int n_in,
                              void* d_out, int out_size, void* d_ws, size_t ws_size,
                              hipStream_t stream) {
    const float* batch = (const float*)d_in[0];
    const float* W = (const float*)d_in[1];
    const float* vb = (const float*)d_in[2];
    const float* hb = (const float*)d_in[3];

    float* ws = (float*)d_ws;
    float* WT = ws;                         // 262144
    float* v_cur = WT + 262144;             // 16777216
    float* h_cur = v_cur + 16777216;        // 4194304 (reused as phk)
    float* ph0 = h_cur + 4194304;           // 4194304
    float* inv = ph0 + 4194304;             // 16384
    float* phk = h_cur;

    float* gw = (float*)d_out;
    float* gvb = gw + (size_t)H_DIM * V_DIM;
    float* ghb = gvb + V_DIM;

    hipMemsetAsync(d_out, 0, (size_t)out_size * sizeof(float), stream);

    // Partitionable threefry split: key(42) = (0,42);
    // subkey[n] = threefry((0,42), (0, n)) -> the two output words ARE the new key.
    // keys reshaped (8,2): step i uses hkey=subkey[2i], vkey=subkey[2i+1].
    uint32_t sk0[16], sk1[16];
    for (int n = 0; n < 16; ++n) {
        threefry2x32(0u, 42u, 0u, (uint32_t)n, &sk0[n], &sk1[n]);
    }

    transpose_w<<<dim3((H_DIM * V_DIM) / 256), dim3(256), 0, stream>>>(W, WT);

    for (int i = 0; i < K_STEPS; ++i) {
        const float* vin = (i == 0) ? batch : v_cur;
        gemm_act<0><<<dim3(B_DIM / 64, H_DIM / 128), dim3(256), 0, stream>>>(
            vin, WT, hb, h_cur, V_DIM, H_DIM, sk0[2 * i], sk1[2 * i]);
        gemm_act<0><<<dim3(B_DIM / 64, V_DIM / 128), dim3(256), 0, stream>>>(
            h_cur, W, vb, v_cur, H_DIM, V_DIM, sk0[2 * i + 1], sk1[2 * i + 1]);
    }
    // positive phase hidden probs from original batch
    gemm_act<1><<<dim3(B_DIM / 64, H_DIM / 128), dim3(256), 0, stream>>>(
        batch, WT, hb, ph0, V_DIM, H_DIM, 0u, 0u);
    // negative phase hidden probs from vk (phk aliases h_cur, now dead)
    gemm_act<1><<<dim3(B_DIM / 64, H_DIM / 128), dim3(256), 0, stream>>>(
        v_cur, WT, hb, phk, V_DIM, H_DIM, 0u, 0u);

    lognorm_kernel<<<dim3(B_DIM), dim3(256), 0, stream>>>(phk, v_cur, vb, inv);
    gw_kernel<<<dim3(H_DIM / 64, V_DIM / 128, 16), dim3(256), 0, stream>>>(
        phk, ph0, v_cur, batch, inv, gw);
    gvb_kernel<<<dim3(V_DIM / 256, B_DIM / 512), dim3(256), 0, stream>>>(
        v_cur, batch, inv, gvb);
    ghb_kernel<<<dim3(B_DIM / 256), dim3(256), 0, stream>>>(phk, ph0, inv, ghb);
}

// Round 3
// 1160.307 us; speedup vs baseline: 2.2645x; 2.2645x over previous
//
#include <hip/hip_runtime.h>
#include <stdint.h>

#define B_DIM 16384
#define V_DIM 1024
#define H_DIM 256
#define K_STEPS 8

typedef short bf16x8 __attribute__((ext_vector_type(8)));
typedef float f32x4 __attribute__((ext_vector_type(4)));

// ---------------- Threefry-2x32-20, bit-exact JAX replica ----------------
__host__ __device__ inline uint32_t rotl32(uint32_t v, int r) {
    return (v << r) | (v >> (32 - r));
}

__host__ __device__ inline void threefry2x32(uint32_t k0, uint32_t k1,
                                             uint32_t x0, uint32_t x1,
                                             uint32_t* o0, uint32_t* o1) {
    uint32_t k2 = k0 ^ k1 ^ 0x1BD11BDAu;
    x0 += k0; x1 += k1;
#define TF_RND(r) { x0 += x1; x1 = rotl32(x1, (r)); x1 ^= x0; }
    TF_RND(13) TF_RND(15) TF_RND(26) TF_RND(6)
    x0 += k1; x1 += k2 + 1u;
    TF_RND(17) TF_RND(29) TF_RND(16) TF_RND(24)
    x0 += k2; x1 += k0 + 2u;
    TF_RND(13) TF_RND(15) TF_RND(26) TF_RND(6)
    x0 += k0; x1 += k1 + 3u;
    TF_RND(17) TF_RND(29) TF_RND(16) TF_RND(24)
    x0 += k1; x1 += k2 + 4u;
    TF_RND(13) TF_RND(15) TF_RND(26) TF_RND(6)
    x0 += k2; x1 += k0 + 5u;
#undef TF_RND
    *o0 = x0; *o1 = x1;
}

// Partitionable-threefry uniform (bits = o0 ^ o1 of counter (0, e)).
__device__ inline float tf_uniform(uint32_t key0, uint32_t key1, uint32_t e) {
    uint32_t o0, o1;
    threefry2x32(key0, key1, 0u, e, &o0, &o1);
    uint32_t bits = o0 ^ o1;
    return __uint_as_float((bits >> 9) | 0x3f800000u) - 1.0f;
}

__device__ inline uint16_t bf16_rn(float f) {
    uint32_t u = __float_as_uint(f);
    uint32_t r = u + 0x7FFFu + ((u >> 16) & 1u);
    return (uint16_t)(r >> 16);
}
__device__ inline float bf16_to_f32(uint16_t h) {
    return __uint_as_float(((uint32_t)h) << 16);
}

__device__ inline void gload_lds16(const void* g, void* l) {
    __builtin_amdgcn_global_load_lds((const __attribute__((address_space(1))) uint32_t*)g,
                                     (__attribute__((address_space(3))) uint32_t*)l, 16, 0, 0);
}

// ---------------- Unified MFMA NT-GEMM ----------------
// C[M x N] = A[M x K] * Bt[N x K]^T (+ bias). 128x128 tile, BK=32, 4 waves 2x2.
// MODE 0: split-B (Bhi+Blo), sigmoid+threefry sample -> bf16 {0,1}
// MODE 1: split-B, sigmoid -> bf16 probs
// MODE 2: single-B, no bias, fp32 atomicAdd into out (K-split via blockIdx.z)
template <int MODE>
__global__ __launch_bounds__(256, 2) void mfma_gemm(
    const ushort* __restrict__ A, const ushort* __restrict__ Bhi,
    const ushort* __restrict__ Blo, const float* __restrict__ bias,
    void* __restrict__ out, int N, int K, int k_slice,
    uint32_t key0, uint32_t key1) {
    __shared__ __align__(16) ushort As[128 * 32];
    __shared__ __align__(16) ushort Bs[128 * 32];
    __shared__ __align__(16) ushort Bs2[128 * 32];

    const int tid = threadIdx.x;
    const int lane = tid & 63;
    const int w = tid >> 6;
    const int m0 = blockIdx.x * 128;
    const int n0 = blockIdx.y * 128;
    const int kbase = blockIdx.z * k_slice;

    f32x4 acc[4][4] = {};

    const int wm = (w & 1) * 64;
    const int wn = (w >> 1) * 64;
    const int q = lane >> 4;
    const int l15 = lane & 15;
    const int srow = lane >> 2;        // 0..15
    const int scol = (lane & 3) * 8;   // k-element offset

    for (int kt = 0; kt < k_slice; kt += 32) {
        const int k0 = kbase + kt;
#pragma unroll
        for (int t2 = 0; t2 < 2; ++t2) {
            int t = w * 2 + t2;
            int row = t * 16 + srow;
            gload_lds16(&A[(size_t)(m0 + row) * K + k0 + scol], &As[t * 512]);
            gload_lds16(&Bhi[(size_t)(n0 + row) * K + k0 + scol], &Bs[t * 512]);
            if (MODE != 2)
                gload_lds16(&Blo[(size_t)(n0 + row) * K + k0 + scol], &Bs2[t * 512]);
        }
        __syncthreads();
        bf16x8 af[4], bh[4], bl[4];
#pragma unroll
        for (int i = 0; i < 4; ++i)
            af[i] = *(const bf16x8*)&As[(wm + i * 16 + l15) * 32 + q * 8];
#pragma unroll
        for (int j = 0; j < 4; ++j) {
            bh[j] = *(const bf16x8*)&Bs[(wn + j * 16 + l15) * 32 + q * 8];
            if (MODE != 2) bl[j] = *(const bf16x8*)&Bs2[(wn + j * 16 + l15) * 32 + q * 8];
        }
#pragma unroll
        for (int i = 0; i < 4; ++i)
#pragma unroll
            for (int j = 0; j < 4; ++j) {
                acc[i][j] = __builtin_amdgcn_mfma_f32_16x16x32_bf16(af[i], bh[j], acc[i][j], 0, 0, 0);
                if (MODE != 2)
                    acc[i][j] = __builtin_amdgcn_mfma_f32_16x16x32_bf16(af[i], bl[j], acc[i][j], 0, 0, 0);
            }
        __syncthreads();
    }

    const int orow = q * 4;
#pragma unroll
    for (int i = 0; i < 4; ++i) {
#pragma unroll
        for (int j = 0; j < 4; ++j) {
            int col = n0 + wn + j * 16 + l15;
            float bv = (MODE == 2) ? 0.0f : bias[col];
#pragma unroll
            for (int r = 0; r < 4; ++r) {
                int row = m0 + wm + i * 16 + orow + r;
                float val = acc[i][j][r] + bv;
                if (MODE == 0) {
                    float sg = 1.0f / (1.0f + expf(-val));
                    uint32_t e = (uint32_t)row * (uint32_t)N + (uint32_t)col;
                    float u = tf_uniform(key0, key1, e);
                    ((ushort*)out)[(size_t)row * N + col] = (u < sg) ? (ushort)0x3F80 : (ushort)0;
                } else if (MODE == 1) {
                    float sg = 1.0f / (1.0f + expf(-val));
                    ((ushort*)out)[(size_t)row * N + col] = bf16_rn(sg);
                } else {
                    atomicAdd(&((float*)out)[(size_t)row * N + col], val);
                }
            }
        }
    }
}

// ---------------- W split into bf16 hi/lo, both layouts ----------------
__global__ void wsplit_kernel(const float* __restrict__ W, ushort* __restrict__ whi,
                              ushort* __restrict__ wlo, ushort* __restrict__ wthi,
                              ushort* __restrict__ wtlo) {
    int idx = blockIdx.x * 256 + threadIdx.x;
    int h = idx >> 10, v = idx & 1023;
    float w = W[idx];
    ushort hi = bf16_rn(w);
    float fhi = bf16_to_f32(hi);
    ushort lo = bf16_rn(w - fhi);
    whi[idx] = hi; wlo[idx] = lo;
    wthi[v * H_DIM + h] = hi; wtlo[v * H_DIM + h] = lo;
}

__global__ void tobf16_kernel(const float* __restrict__ src, ushort* __restrict__ dst) {
    int idx = blockIdx.x * 256 + threadIdx.x;  // over n/4
    float4 f = ((const float4*)src)[idx];
    ushort4 o;
    o.x = bf16_rn(f.x); o.y = bf16_rn(f.y); o.z = bf16_rn(f.z); o.w = bf16_rn(f.w);
    ((ushort4*)dst)[idx] = o;
}

// ---------------- log-norm ----------------
__global__ __launch_bounds__(256) void lognorm_kernel(
    const ushort* __restrict__ phk, const ushort* __restrict__ vk,
    const float* __restrict__ vb, float* __restrict__ inv) {
    int b = blockIdx.x;
    int tid = threadIdx.x;
    float p = bf16_to_f32(phk[(size_t)b * H_DIM + tid]);
    float s = -log1pf(-p);
    for (int j = tid; j < V_DIM; j += 256)
        s += bf16_to_f32(vk[(size_t)b * V_DIM + j]) * vb[j];
    for (int off = 32; off > 0; off >>= 1) s += __shfl_down(s, off, 64);
    __shared__ float wsum[4];
    int lane = tid & 63, wid = tid >> 6;
    if (lane == 0) wsum[wid] = s;
    __syncthreads();
    if (tid == 0) {
        float t = wsum[0] + wsum[1] + wsum[2] + wsum[3];
        inv[b] = expf(-t) * (1.0f / 16384.0f);
    }
}

// ---------------- transposes for gw GEMM ----------------
// At[h][b] = sgn * inv[b] * P[b][h]  (P bf16 [B][H]); At bf16 [H][B]
__global__ void build_At(const ushort* __restrict__ P, const float* __restrict__ inv,
                         float sgn, ushort* __restrict__ At) {
    __shared__ float T[64][65];
    int c = threadIdx.x & 63;
    int rb = threadIdx.x >> 6;
    int b0 = blockIdx.x * 64;
    int h0 = blockIdx.y * 64;
    for (int r = rb; r < 64; r += 4) {
        int b = b0 + r;
        T[c][r] = sgn * inv[b] * bf16_to_f32(P[(size_t)b * H_DIM + h0 + c]);
    }
    __syncthreads();
    for (int r = rb; r < 64; r += 4)
        At[(size_t)(h0 + r) * B_DIM + b0 + c] = bf16_rn(T[r][c]);
}

// Bt[v][b] = src[b][v]; src bf16 (Sb) or fp32 (Sf)
__global__ void build_Bt(const ushort* __restrict__ Sb, const float* __restrict__ Sf,
                         int use_f32, ushort* __restrict__ Bt) {
    __shared__ ushort T[64][65];
    int c = threadIdx.x & 63;
    int rb = threadIdx.x >> 6;
    int b0 = blockIdx.x * 64;
    int v0 = blockIdx.y * 64;
    for (int r = rb; r < 64; r += 4) {
        int b = b0 + r;
        T[c][r] = use_f32 ? bf16_rn(Sf[(size_t)b * V_DIM + v0 + c])
                          : Sb[(size_t)b * V_DIM + v0 + c];
    }
    __syncthreads();
    for (int r = rb; r < 64; r += 4)
        Bt[(size_t)(v0 + r) * B_DIM + b0 + c] = T[r][c];
}

// ---------------- g_vb / g_hb ----------------
__global__ void gvb_kernel(const ushort* __restrict__ vk, const float* __restrict__ batch,
                           const float* __restrict__ inv, float* __restrict__ gvb) {
    int col = blockIdx.x * 256 + threadIdx.x;
    int b0 = blockIdx.y * 512;
    float acc = 0.0f;
    for (int r = 0; r < 512; ++r) {
        int b = b0 + r;
        acc += inv[b] * (bf16_to_f32(vk[(size_t)b * V_DIM + col]) - batch[(size_t)b * V_DIM + col]);
    }
    atomicAdd(&gvb[col], acc);
}

__global__ void ghb_kernel(const ushort* __restrict__ phk, const ushort* __restrict__ ph0,
                           const float* __restrict__ inv, float* __restrict__ ghb) {
    int col = threadIdx.x;
    int b0 = blockIdx.x * 256;
    float acc = 0.0f;
    for (int r = 0; r < 256; ++r) {
        int b = b0 + r;
        acc += inv[b] * (bf16_to_f32(phk[(size_t)b * H_DIM + col]) -
                         bf16_to_f32(ph0[(size_t)b * H_DIM + col]));
    }
    atomicAdd(&ghb[col], acc);
}

extern "C" void kernel_launch(void* const* d_in, const int* in_sizes, int n_in,
                              void* d_out, int out_size, void* d_ws, size_t ws_size,
                              hipStream_t stream) {
    const float* batch = (const float*)d_in[0];
    const float* W = (const float*)d_in[1];
    const float* vb = (const float*)d_in[2];
    const float* hb = (const float*)d_in[3];

    char* base = (char*)d_ws;
    ushort* w_hi  = (ushort*)(base + 0);          // 512 KB
    ushort* w_lo  = (ushort*)(base + 524288);
    ushort* wt_hi = (ushort*)(base + 1048576);
    ushort* wt_lo = (ushort*)(base + 1572864);
    ushort* v_cur = (ushort*)(base + 2097152);    // 32 MB
    float*  inv   = (float*)(base + 35651584);    // 64 KB
    ushort* h_cur = (ushort*)(base + 35717120);   // 8 MB (aliased: At after loop)
    ushort* At    = h_cur;
    ushort* batch_bf = (ushort*)(base + 44105728); // 32 MB (aliased: Bt after ph0 gemm)
    ushort* Bt    = batch_bf;
    ushort* ph0b  = (ushort*)(base + 77660160);   // 8 MB
    ushort* phkb  = (ushort*)(base + 86048768);   // 8 MB -> total 94437376 B

    float* gw  = (float*)d_out;
    float* gvb = gw + (size_t)H_DIM * V_DIM;
    float* ghb = gvb + V_DIM;

    hipMemsetAsync(d_out, 0, (size_t)out_size * sizeof(float), stream);

    // Partitionable threefry split of key(42): subkey[n] = threefry((0,42),(0,n)).
    uint32_t sk0[16], sk1[16];
    for (int n = 0; n < 16; ++n) threefry2x32(0u, 42u, 0u, (uint32_t)n, &sk0[n], &sk1[n]);

    wsplit_kernel<<<dim3(1024), dim3(256), 0, stream>>>(W, w_hi, w_lo, wt_hi, wt_lo);
    tobf16_kernel<<<dim3(B_DIM * V_DIM / 4 / 256), dim3(256), 0, stream>>>(batch, batch_bf);

    for (int i = 0; i < K_STEPS; ++i) {
        const ushort* vin = (i == 0) ? batch_bf : v_cur;
        mfma_gemm<0><<<dim3(128, 2, 1), dim3(256), 0, stream>>>(
            vin, w_hi, w_lo, hb, h_cur, H_DIM, V_DIM, V_DIM, sk0[2 * i], sk1[2 * i]);
        mfma_gemm<0><<<dim3(128, 8, 1), dim3(256), 0, stream>>>(
            h_cur, wt_hi, wt_lo, vb, v_cur, V_DIM, H_DIM, H_DIM, sk0[2 * i + 1], sk1[2 * i + 1]);
    }
    // probs (bf16): ph0 from batch, phk from vk
    mfma_gemm<1><<<dim3(128, 2, 1), dim3(256), 0, stream>>>(
        batch_bf, w_hi, w_lo, hb, ph0b, H_DIM, V_DIM, V_DIM, 0u, 0u);
    mfma_gemm<1><<<dim3(128, 2, 1), dim3(256), 0, stream>>>(
        v_cur, w_hi, w_lo, hb, phkb, H_DIM, V_DIM, V_DIM, 0u, 0u);

    lognorm_kernel<<<dim3(B_DIM), dim3(256), 0, stream>>>(phkb, v_cur, vb, inv);
    ghb_kernel<<<dim3(B_DIM / 256), dim3(256), 0, stream>>>(phkb, ph0b, inv, ghb);
    gvb_kernel<<<dim3(V_DIM / 256, B_DIM / 512), dim3(256), 0, stream>>>(v_cur, batch, inv, gvb);

    // g_W positive phase: At = inv*phk^T, Bt = vk^T (Bt overwrites batch_bf, h_cur->At dead)
    build_At<<<dim3(B_DIM / 64, H_DIM / 64), dim3(256), 0, stream>>>(phkb, inv, 1.0f, At);
    build_Bt<<<dim3(B_DIM / 64, V_DIM / 64), dim3(256), 0, stream>>>(v_cur, nullptr, 0, Bt);
    mfma_gemm<2><<<dim3(2, 8, 16), dim3(256), 0, stream>>>(
        At, Bt, nullptr, nullptr, gw, V_DIM, B_DIM, 1024, 0u, 0u);
    // g_W negative phase: At = -inv*ph0^T, Bt = batch^T (from pristine fp32 input)
    build_At<<<dim3(B_DIM / 64, H_DIM / 64), dim3(256), 0, stream>>>(ph0b, inv, -1.0f, At);
    build_Bt<<<dim3(B_DIM / 64, V_DIM / 64), dim3(256), 0, stream>>>(nullptr, batch, 1, Bt);
    mfma_gemm<2><<<dim3(2, 8, 16), dim3(256), 0, stream>>>(
        At, Bt, nullptr, nullptr, gw, V_DIM, B_DIM, 1024, 0u, 0u);
}

// Round 4
// 1030.277 us; speedup vs baseline: 2.5502x; 1.1262x over previous
//
#include <hip/hip_runtime.h>
#include <stdint.h>

#define B_DIM 16384
#define V_DIM 1024
#define H_DIM 256
#define K_STEPS 8

typedef short bf16x8 __attribute__((ext_vector_type(8)));
typedef float f32x4 __attribute__((ext_vector_type(4)));

// ---------------- Threefry-2x32-20, bit-exact JAX replica ----------------
__host__ __device__ inline uint32_t rotl32(uint32_t v, int r) {
    return (v << r) | (v >> (32 - r));
}

__host__ __device__ inline void threefry2x32(uint32_t k0, uint32_t k1,
                                             uint32_t x0, uint32_t x1,
                                             uint32_t* o0, uint32_t* o1) {
    uint32_t k2 = k0 ^ k1 ^ 0x1BD11BDAu;
    x0 += k0; x1 += k1;
#define TF_RND(r) { x0 += x1; x1 = rotl32(x1, (r)); x1 ^= x0; }
    TF_RND(13) TF_RND(15) TF_RND(26) TF_RND(6)
    x0 += k1; x1 += k2 + 1u;
    TF_RND(17) TF_RND(29) TF_RND(16) TF_RND(24)
    x0 += k2; x1 += k0 + 2u;
    TF_RND(13) TF_RND(15) TF_RND(26) TF_RND(6)
    x0 += k0; x1 += k1 + 3u;
    TF_RND(17) TF_RND(29) TF_RND(16) TF_RND(24)
    x0 += k1; x1 += k2 + 4u;
    TF_RND(13) TF_RND(15) TF_RND(26) TF_RND(6)
    x0 += k2; x1 += k0 + 5u;
#undef TF_RND
    *o0 = x0; *o1 = x1;
}

// Partitionable-threefry uniform (bits = o0 ^ o1 of counter (0, e)).
__device__ inline float tf_uniform(uint32_t key0, uint32_t key1, uint32_t e) {
    uint32_t o0, o1;
    threefry2x32(key0, key1, 0u, e, &o0, &o1);
    uint32_t bits = o0 ^ o1;
    return __uint_as_float((bits >> 9) | 0x3f800000u) - 1.0f;
}

__device__ inline uint16_t bf16_rn(float f) {
    uint32_t u = __float_as_uint(f);
    uint32_t r = u + 0x7FFFu + ((u >> 16) & 1u);
    return (uint16_t)(r >> 16);
}
__device__ inline float bf16_to_f32(uint16_t h) {
    return __uint_as_float(((uint32_t)h) << 16);
}

__device__ inline void gload_lds16(const void* g, void* l) {
    __builtin_amdgcn_global_load_lds((const __attribute__((address_space(1))) uint32_t*)g,
                                     (__attribute__((address_space(3))) uint32_t*)l, 16, 0, 0);
}

// ---------------- Unified MFMA NT-GEMM, 64x64 tile ----------------
// C[M x N] = A[M x K] * Bt[N x K]^T (+ bias). 4 waves, each 32x32 (2x2 frags).
// MODE 0: split-B (Bhi+Blo), sigmoid + threefry sample -> bf16 {0,1}
// MODE 1: split-B, sigmoid -> bf16 probs
// MODE 2: single-B, no bias, fp32 atomicAdd into out (K-split via blockIdx.z)
// MODE 3: split-B, sample -> out AND probs -> out2
template <int MODE>
__global__ __launch_bounds__(256, 4) void mfma_gemm(
    const ushort* __restrict__ A, const ushort* __restrict__ Bhi,
    const ushort* __restrict__ Blo, const float* __restrict__ bias,
    void* __restrict__ out, ushort* __restrict__ out2,
    int N, int K, int k_slice, uint32_t key0, uint32_t key1) {
    __shared__ __align__(16) ushort As[64 * 32];
    __shared__ __align__(16) ushort Bs[64 * 32];
    __shared__ __align__(16) ushort Bs2[64 * 32];

    const int tid = threadIdx.x;
    const int lane = tid & 63;
    const int w = tid >> 6;
    const int m0 = blockIdx.x * 64;
    const int n0 = blockIdx.y * 64;
    const int kbase = blockIdx.z * k_slice;

    f32x4 acc[2][2] = {};

    const int wm = (w & 1) * 32;
    const int wn = (w >> 1) * 32;
    const int q = lane >> 4;
    const int l15 = lane & 15;
    const int srow = lane >> 2;       // 0..15
    const int scol = (lane & 3) * 8;  // k-element offset

    const size_t arow = (size_t)(m0 + w * 16 + srow) * K;
    const size_t brow = (size_t)(n0 + w * 16 + srow) * K;

    for (int kt = 0; kt < k_slice; kt += 32) {
        const int k0 = kbase + kt;
        gload_lds16(&A[arow + k0 + scol], &As[w * 512]);
        gload_lds16(&Bhi[brow + k0 + scol], &Bs[w * 512]);
        if (MODE != 2) gload_lds16(&Blo[brow + k0 + scol], &Bs2[w * 512]);
        __syncthreads();
        bf16x8 af[2], bh[2], bl[2];
#pragma unroll
        for (int i = 0; i < 2; ++i)
            af[i] = *(const bf16x8*)&As[(wm + i * 16 + l15) * 32 + q * 8];
#pragma unroll
        for (int j = 0; j < 2; ++j) {
            bh[j] = *(const bf16x8*)&Bs[(wn + j * 16 + l15) * 32 + q * 8];
            if (MODE != 2) bl[j] = *(const bf16x8*)&Bs2[(wn + j * 16 + l15) * 32 + q * 8];
        }
#pragma unroll
        for (int i = 0; i < 2; ++i)
#pragma unroll
            for (int j = 0; j < 2; ++j) {
                acc[i][j] = __builtin_amdgcn_mfma_f32_16x16x32_bf16(af[i], bh[j], acc[i][j], 0, 0, 0);
                if (MODE != 2)
                    acc[i][j] = __builtin_amdgcn_mfma_f32_16x16x32_bf16(af[i], bl[j], acc[i][j], 0, 0, 0);
            }
        __syncthreads();
    }

    const int orow = q * 4;
#pragma unroll
    for (int i = 0; i < 2; ++i) {
#pragma unroll
        for (int j = 0; j < 2; ++j) {
            int col = n0 + wn + j * 16 + l15;
            float bv = (MODE == 2) ? 0.0f : bias[col];
#pragma unroll
            for (int r = 0; r < 4; ++r) {
                int row = m0 + wm + i * 16 + orow + r;
                float val = acc[i][j][r] + bv;
                if (MODE == 0 || MODE == 3) {
                    float sg = 1.0f / (1.0f + expf(-val));
                    uint32_t e = (uint32_t)row * (uint32_t)N + (uint32_t)col;
                    float u = tf_uniform(key0, key1, e);
                    ((ushort*)out)[(size_t)row * N + col] = (u < sg) ? (ushort)0x3F80 : (ushort)0;
                    if (MODE == 3) out2[(size_t)row * N + col] = bf16_rn(sg);
                } else if (MODE == 1) {
                    float sg = 1.0f / (1.0f + expf(-val));
                    ((ushort*)out)[(size_t)row * N + col] = bf16_rn(sg);
                } else {
                    atomicAdd(&((float*)out)[(size_t)row * N + col], val);
                }
            }
        }
    }
}

// ---------------- W split into bf16 hi/lo, both layouts ----------------
__global__ void wsplit_kernel(const float* __restrict__ W, ushort* __restrict__ whi,
                              ushort* __restrict__ wlo, ushort* __restrict__ wthi,
                              ushort* __restrict__ wtlo) {
    int idx = blockIdx.x * 256 + threadIdx.x;
    int h = idx >> 10, v = idx & 1023;
    float w = W[idx];
    ushort hi = bf16_rn(w);
    float fhi = bf16_to_f32(hi);
    ushort lo = bf16_rn(w - fhi);
    whi[idx] = hi; wlo[idx] = lo;
    wthi[v * H_DIM + h] = hi; wtlo[v * H_DIM + h] = lo;
}

__global__ void tobf16_kernel(const float* __restrict__ src, ushort* __restrict__ dst) {
    int idx = blockIdx.x * 256 + threadIdx.x;  // over n/4
    float4 f = ((const float4*)src)[idx];
    ushort4 o;
    o.x = bf16_rn(f.x); o.y = bf16_rn(f.y); o.z = bf16_rn(f.z); o.w = bf16_rn(f.w);
    ((ushort4*)dst)[idx] = o;
}

// ---------------- log-norm ----------------
__global__ __launch_bounds__(256) void lognorm_kernel(
    const ushort* __restrict__ phk, const ushort* __restrict__ vk,
    const float* __restrict__ vb, float* __restrict__ inv) {
    int b = blockIdx.x;
    int tid = threadIdx.x;
    float p = bf16_to_f32(phk[(size_t)b * H_DIM + tid]);
    float s = -log1pf(-p);
    for (int j = tid; j < V_DIM; j += 256)
        s += bf16_to_f32(vk[(size_t)b * V_DIM + j]) * vb[j];
    for (int off = 32; off > 0; off >>= 1) s += __shfl_down(s, off, 64);
    __shared__ float wsum[4];
    int lane = tid & 63, wid = tid >> 6;
    if (lane == 0) wsum[wid] = s;
    __syncthreads();
    if (tid == 0) {
        float t = wsum[0] + wsum[1] + wsum[2] + wsum[3];
        inv[b] = expf(-t) * (1.0f / 16384.0f);
    }
}

// ---------------- transposes for gw GEMM ----------------
// At[h][b] = sgn * inv[b] * P[b][h]  (P bf16 [B][H]); At bf16 [H][B]
__global__ void build_At(const ushort* __restrict__ P, const float* __restrict__ inv,
                         float sgn, ushort* __restrict__ At) {
    __shared__ float T[64][65];
    int c = threadIdx.x & 63;
    int rb = threadIdx.x >> 6;
    int b0 = blockIdx.x * 64;
    int h0 = blockIdx.y * 64;
    for (int r = rb; r < 64; r += 4) {
        int b = b0 + r;
        T[c][r] = sgn * inv[b] * bf16_to_f32(P[(size_t)b * H_DIM + h0 + c]);
    }
    __syncthreads();
    for (int r = rb; r < 64; r += 4)
        At[(size_t)(h0 + r) * B_DIM + b0 + c] = bf16_rn(T[r][c]);
}

// Bt[v][b] = src[b][v]; src bf16 (Sb) or fp32 (Sf)
__global__ void build_Bt(const ushort* __restrict__ Sb, const float* __restrict__ Sf,
                         int use_f32, ushort* __restrict__ Bt) {
    __shared__ ushort T[64][65];
    int c = threadIdx.x & 63;
    int rb = threadIdx.x >> 6;
    int b0 = blockIdx.x * 64;
    int v0 = blockIdx.y * 64;
    for (int r = rb; r < 64; r += 4) {
        int b = b0 + r;
        T[c][r] = use_f32 ? bf16_rn(Sf[(size_t)b * V_DIM + v0 + c])
                          : Sb[(size_t)b * V_DIM + v0 + c];
    }
    __syncthreads();
    for (int r = rb; r < 64; r += 4)
        Bt[(size_t)(v0 + r) * B_DIM + b0 + c] = T[r][c];
}

// ---------------- g_vb / g_hb ----------------
__global__ void gvb_kernel(const ushort* __restrict__ vk, const ushort* __restrict__ vbat,
                           const float* __restrict__ inv, float* __restrict__ gvb) {
    int col = blockIdx.x * 256 + threadIdx.x;
    int b0 = blockIdx.y * 512;
    float acc = 0.0f;
    for (int r = 0; r < 512; ++r) {
        int b = b0 + r;
        acc += inv[b] * (bf16_to_f32(vk[(size_t)b * V_DIM + col]) -
                         bf16_to_f32(vbat[(size_t)b * V_DIM + col]));
    }
    atomicAdd(&gvb[col], acc);
}

__global__ void ghb_kernel(const ushort* __restrict__ phk, const ushort* __restrict__ ph0,
                           const float* __restrict__ inv, float* __restrict__ ghb) {
    int col = threadIdx.x;
    int b0 = blockIdx.x * 256;
    float acc = 0.0f;
    for (int r = 0; r < 256; ++r) {
        int b = b0 + r;
        acc += inv[b] * (bf16_to_f32(phk[(size_t)b * H_DIM + col]) -
                         bf16_to_f32(ph0[(size_t)b * H_DIM + col]));
    }
    atomicAdd(&ghb[col], acc);
}

extern "C" void kernel_launch(void* const* d_in, const int* in_sizes, int n_in,
                              void* d_out, int out_size, void* d_ws, size_t ws_size,
                              hipStream_t stream) {
    const float* batch = (const float*)d_in[0];
    const float* W = (const float*)d_in[1];
    const float* vb = (const float*)d_in[2];
    const float* hb = (const float*)d_in[3];

    char* base = (char*)d_ws;
    ushort* w_hi  = (ushort*)(base + 0);          // 512 KB
    ushort* w_lo  = (ushort*)(base + 524288);
    ushort* wt_hi = (ushort*)(base + 1048576);
    ushort* wt_lo = (ushort*)(base + 1572864);
    ushort* v_cur = (ushort*)(base + 2097152);    // 32 MB
    float*  inv   = (float*)(base + 35651584);    // 64 KB
    ushort* h_cur = (ushort*)(base + 35717120);   // 8 MB (aliased: At after loop)
    ushort* At    = h_cur;
    ushort* batch_bf = (ushort*)(base + 44105728); // 32 MB (aliased: Bt after last use)
    ushort* Bt    = batch_bf;
    ushort* ph0b  = (ushort*)(base + 77660160);   // 8 MB
    ushort* phkb  = (ushort*)(base + 86048768);   // 8 MB -> total 94437376 B

    float* gw  = (float*)d_out;
    float* gvb = gw + (size_t)H_DIM * V_DIM;
    float* ghb = gvb + V_DIM;

    hipMemsetAsync(d_out, 0, (size_t)out_size * sizeof(float), stream);

    // Partitionable threefry split of key(42): subkey[n] = threefry((0,42),(0,n)).
    uint32_t sk0[16], sk1[16];
    for (int n = 0; n < 16; ++n) threefry2x32(0u, 42u, 0u, (uint32_t)n, &sk0[n], &sk1[n]);

    wsplit_kernel<<<dim3(1024), dim3(256), 0, stream>>>(W, w_hi, w_lo, wt_hi, wt_lo);
    tobf16_kernel<<<dim3(B_DIM * V_DIM / 4 / 256), dim3(256), 0, stream>>>(batch, batch_bf);

    for (int i = 0; i < K_STEPS; ++i) {
        const ushort* vin = (i == 0) ? batch_bf : v_cur;
        if (i == 0) {
            // fused: sample h AND store ph0 probs (same GEMM, batch input)
            mfma_gemm<3><<<dim3(B_DIM / 64, H_DIM / 64, 1), dim3(256), 0, stream>>>(
                vin, w_hi, w_lo, hb, h_cur, ph0b, H_DIM, V_DIM, V_DIM, sk0[0], sk1[0]);
        } else {
            mfma_gemm<0><<<dim3(B_DIM / 64, H_DIM / 64, 1), dim3(256), 0, stream>>>(
                vin, w_hi, w_lo, hb, h_cur, nullptr, H_DIM, V_DIM, V_DIM, sk0[2 * i], sk1[2 * i]);
        }
        mfma_gemm<0><<<dim3(B_DIM / 64, V_DIM / 64, 1), dim3(256), 0, stream>>>(
            h_cur, wt_hi, wt_lo, vb, v_cur, nullptr, V_DIM, H_DIM, H_DIM, sk0[2 * i + 1], sk1[2 * i + 1]);
    }
    // negative phase hidden probs from vk
    mfma_gemm<1><<<dim3(B_DIM / 64, H_DIM / 64, 1), dim3(256), 0, stream>>>(
        v_cur, w_hi, w_lo, hb, phkb, nullptr, H_DIM, V_DIM, V_DIM, 0u, 0u);

    lognorm_kernel<<<dim3(B_DIM), dim3(256), 0, stream>>>(phkb, v_cur, vb, inv);
    ghb_kernel<<<dim3(B_DIM / 256), dim3(256), 0, stream>>>(phkb, ph0b, inv, ghb);
    gvb_kernel<<<dim3(V_DIM / 256, B_DIM / 512), dim3(256), 0, stream>>>(v_cur, batch_bf, inv, gvb);

    // g_W positive phase: At = inv*phk^T, Bt = vk^T (Bt overwrites batch_bf)
    build_At<<<dim3(B_DIM / 64, H_DIM / 64), dim3(256), 0, stream>>>(phkb, inv, 1.0f, At);
    build_Bt<<<dim3(B_DIM / 64, V_DIM / 64), dim3(256), 0, stream>>>(v_cur, nullptr, 0, Bt);
    mfma_gemm<2><<<dim3(H_DIM / 64, V_DIM / 64, 16), dim3(256), 0, stream>>>(
        At, Bt, nullptr, nullptr, gw, nullptr, V_DIM, B_DIM, 1024, 0u, 0u);
    // g_W negative phase: At = -inv*ph0^T, Bt = batch^T (from pristine fp32 input)
    build_At<<<dim3(B_DIM / 64, H_DIM / 64), dim3(256), 0, stream>>>(ph0b, inv, -1.0f, At);
    build_Bt<<<dim3(B_DIM / 64, V_DIM / 64), dim3(256), 0, stream>>>(nullptr, batch, 1, Bt);
    mfma_gemm<2><<<dim3(H_DIM / 64, V_DIM / 64, 16), dim3(256), 0, stream>>>(
        At, Bt, nullptr, nullptr, gw, nullptr, V_DIM, B_DIM, 1024, 0u, 0u);
}